// Round 13
// baseline (170.074 us; speedup 1.0000x reference)
//
#include <hip/hip_runtime.h>
#include <hip/hip_bf16.h>

#define B_ 8
#define K_ 8
#define H_ 256
#define W_ 256
#define HW (H_*W_)

// ---------------------------------------------------------------------------
// helpers
// ---------------------------------------------------------------------------
__device__ __forceinline__ unsigned short f2bf(float f) {
    __hip_bfloat16 h = __float2bfloat16(f);  // RNE
    return *reinterpret_cast<unsigned short*>(&h);
}
// unpack 8 bf16 (elem 2k in low 16 bits, 2k+1 in high) to f32
__device__ __forceinline__ void ub8(uint4 u, float* o) {
    o[0] = __uint_as_float(u.x << 16); o[1] = __uint_as_float(u.x & 0xffff0000u);
    o[2] = __uint_as_float(u.y << 16); o[3] = __uint_as_float(u.y & 0xffff0000u);
    o[4] = __uint_as_float(u.z << 16); o[5] = __uint_as_float(u.z & 0xffff0000u);
    o[6] = __uint_as_float(u.w << 16); o[7] = __uint_as_float(u.w & 0xffff0000u);
}
// sum within each 32-lane half of a wave; result valid in lanes 0 and 32
__device__ __forceinline__ float half_reduce(float v) {
    v += __shfl_down(v, 16, 64);
    v += __shfl_down(v, 8, 64);
    v += __shfl_down(v, 4, 64);
    v += __shfl_down(v, 2, 64);
    v += __shfl_down(v, 1, 64);
    return v;
}

// per-pixel warp + bilinear + residual; accumulates into aa[8]
__device__ __forceinline__ void pixel_accum(
    const uint4* __restrict__ imgT, const uint4* __restrict__ TG,
    int b, int x, int y,
    float h00, float h01, float h02, float h10, float h11, float h12,
    float h20, float h21, float* aa) {
    const int px = (y << 8) | x;
    const float X = (float)x - 127.5f, Y = (float)y - 127.5f;
    const float zw = h20 * X + h21 * Y + 1.f;
    const float Xw = (h00 * X + h01 * Y + h02) / zw + 127.5f;
    const float Yw = (h10 * X + h11 * Y + h12) / zw + 127.5f;
    const float NLO = -1.f + 2.f / 256.f, NHI = 1.f - 2.f / 256.f;
    const float xn = Xw / 127.5f - 1.f, yn = Yw / 127.5f - 1.f;
    const float m = (xn > NLO && xn < NHI && yn > NLO && yn < NHI) ? 1.f : 0.f;

    const float x0f = floorf(Xw), y0f = floorf(Yw);
    const float fx = Xw - x0f, fy = Yw - y0f;
    const float x1f = x0f + 1.f, y1f = y0f + 1.f;
    const bool vx0 = (x0f >= 0.f) && (x0f <= 255.f);
    const bool vx1 = (x1f >= 0.f) && (x1f <= 255.f);
    const bool vy0 = (y0f >= 0.f) && (y0f <= 255.f);
    const bool vy1 = (y1f >= 0.f) && (y1f <= 255.f);
    const int xi0 = (int)fminf(fmaxf(x0f, 0.f), 255.f);
    const int xi1 = (int)fminf(fmaxf(x1f, 0.f), 255.f);
    const int yi0 = (int)fminf(fmaxf(y0f, 0.f), 255.f);
    const int yi1 = (int)fminf(fmaxf(y1f, 0.f), 255.f);
    const int i00 = yi0 * W_ + xi0, i01 = yi0 * W_ + xi1;
    const int i10 = yi1 * W_ + xi0, i11 = yi1 * W_ + xi1;
    const float w00 = ((vx0 && vy0) ? 1.f : 0.f) * (1.f - fx) * (1.f - fy);
    const float w01 = ((vx1 && vy0) ? 1.f : 0.f) * fx * (1.f - fy);
    const float w10 = ((vx0 && vy1) ? 1.f : 0.f) * (1.f - fx) * fy;
    const float w11 = ((vx1 && vy1) ? 1.f : 0.f) * fx * fy;

    const int base = b * HW;
    const uint4 u00 = imgT[base + i00], u01 = imgT[base + i01];
    const uint4 u10 = imgT[base + i10], u11 = imgT[base + i11];
    const uint4* tg = TG + (size_t)(base + px) * 3;
    const uint4 t0 = tg[0], g0 = tg[1], g1 = tg[2];

    float A00[8], A01[8], A10[8], A11[8], GX[8], GY[8], TV[8];
    ub8(u00, A00); ub8(u01, A01); ub8(u10, A10); ub8(u11, A11);
    ub8(t0, TV);   ub8(g0, GX);   ub8(g1, GY);

    float vx = 0.f, vy = 0.f;
    #pragma unroll
    for (int c = 0; c < 8; ++c) {
        const float Q = w00 * A00[c] + w01 * A01[c] + w10 * A10[c] + w11 * A11[c];
        const float r = Q - TV[c] * m;
        vx += GX[c] * r;
        vy += GY[c] * r;
    }
    const float t0a = X * vx, t4a = Y * vy;
    const float cc = t0a + t4a;
    aa[0] += t0a;      aa[1] += Y * vx;  aa[2] += vx;
    aa[3] += X * vy;   aa[4] += t4a;     aa[5] += vy;
    aa[6] -= X * cc;   aa[7] -= Y * cc;
}

// ---------------------------------------------------------------------------
// prep: transpose img/temp to channel-interleaved bf16 + grads; Gram via
// 15 row-moments; AND iteration-0 residual partials (identity-warp fast path
// when init_param==0; general planar-gather fallback otherwise).
// grid = B_*H_ blocks, 256 thr, one (b,y) row per block.
// ---------------------------------------------------------------------------
__global__ __launch_bounds__(256) void prep_kernel(
    const float* __restrict__ img, const float* __restrict__ temp,
    const float* __restrict__ init_param,
    uint4* __restrict__ imgT, uint4* __restrict__ TG,
    double* __restrict__ gramP, float* __restrict__ sPrep) {
    __shared__ float smem[8192];
    __shared__ float s15[15];
    __shared__ float sh_p0[8];
    const int b   = blockIdx.x & 7;
    const int y   = blockIdx.x >> 3;
    const int tid = threadIdx.x;
    const int ym = (y > 0) ? y - 1 : 0;
    const int yp = (y < 255) ? y + 1 : 255;

    #pragma unroll
    for (int j = 0; j < 8; ++j) {
        const int slot = tid + 256 * j;
        const int rowid = slot >> 6, col4 = slot & 63;
        const int c = rowid >> 2, sel = rowid & 3;
        const int sy = (sel == 0) ? ym : ((sel == 2) ? yp : y);
        const float* src = ((sel == 3) ? img : temp)
                         + ((size_t)(b * K_ + c) * HW + sy * W_ + col4 * 4);
        const float4 v = *(const float4*)src;
        *(float4*)&smem[(c * 4 + sel) * 256 + col4 * 4] = v;
    }
    if (tid < 8) sh_p0[tid] = init_param[b * 8 + tid];
    __syncthreads();

    const int x = tid;
    const int px = (y << 8) | x;
    const float X = (float)x - 127.5f, Y = (float)y - 127.5f;
    const int xm = (x > 0) ? x - 1 : 0;
    const int xp = (x < 255) ? x + 1 : 255;

    // iter-0 warp setup: fast path (p0==0 -> identity) or general fallback
    const bool pzero = (sh_p0[0] == 0.f) && (sh_p0[1] == 0.f) && (sh_p0[2] == 0.f)
                    && (sh_p0[3] == 0.f) && (sh_p0[4] == 0.f) && (sh_p0[5] == 0.f)
                    && (sh_p0[6] == 0.f) && (sh_p0[7] == 0.f);
    float mm = ((x >= 1) && (x <= 254) && (y >= 1) && (y <= 254)) ? 1.f : 0.f;
    float w00 = 0.f, w01 = 0.f, w10 = 0.f, w11 = 0.f;
    int i00 = 0, i01 = 0, i10 = 0, i11 = 0;
    if (!pzero) {
        const float h00 = 1.f + sh_p0[0], h01 = sh_p0[1], h02 = sh_p0[2];
        const float h10 = sh_p0[3], h11 = 1.f + sh_p0[4], h12 = sh_p0[5];
        const float h20 = sh_p0[6], h21 = sh_p0[7];
        const float zw = h20 * X + h21 * Y + 1.f;
        const float Xw = (h00 * X + h01 * Y + h02) / zw + 127.5f;
        const float Yw = (h10 * X + h11 * Y + h12) / zw + 127.5f;
        const float NLO = -1.f + 2.f / 256.f, NHI = 1.f - 2.f / 256.f;
        const float xn = Xw / 127.5f - 1.f, yn = Yw / 127.5f - 1.f;
        mm = (xn > NLO && xn < NHI && yn > NLO && yn < NHI) ? 1.f : 0.f;
        const float x0f = floorf(Xw), y0f = floorf(Yw);
        const float fx = Xw - x0f, fy = Yw - y0f;
        const float x1f = x0f + 1.f, y1f = y0f + 1.f;
        const bool vx0 = (x0f >= 0.f) && (x0f <= 255.f);
        const bool vx1 = (x1f >= 0.f) && (x1f <= 255.f);
        const bool vy0 = (y0f >= 0.f) && (y0f <= 255.f);
        const bool vy1 = (y1f >= 0.f) && (y1f <= 255.f);
        const int xi0 = (int)fminf(fmaxf(x0f, 0.f), 255.f);
        const int xi1 = (int)fminf(fmaxf(x1f, 0.f), 255.f);
        const int yi0 = (int)fminf(fmaxf(y0f, 0.f), 255.f);
        const int yi1 = (int)fminf(fmaxf(y1f, 0.f), 255.f);
        i00 = yi0 * W_ + xi0; i01 = yi0 * W_ + xi1;
        i10 = yi1 * W_ + xi0; i11 = yi1 * W_ + xi1;
        w00 = ((vx0 && vy0) ? 1.f : 0.f) * (1.f - fx) * (1.f - fy);
        w01 = ((vx1 && vy0) ? 1.f : 0.f) * fx * (1.f - fy);
        w10 = ((vx0 && vy1) ? 1.f : 0.f) * (1.f - fx) * fy;
        w11 = ((vx1 && vy1) ? 1.f : 0.f) * fx * fy;
    }

    float Sxx = 0.f, Sxy = 0.f, Syy = 0.f;
    float vx = 0.f, vy = 0.f;
    unsigned int imgp[4] = {0, 0, 0, 0};
    unsigned int tgp[12];
    #pragma unroll
    for (int i = 0; i < 12; ++i) tgp[i] = 0u;
    #pragma unroll
    for (int c = 0; c < 8; ++c) {
        const float* R = &smem[c * 1024];
        const float gx = 0.5f * (R[256 + xp] - R[256 + xm]);
        const float gy = 0.5f * (R[512 + x] - R[x]);
        const float tc = R[256 + x];
        const float iv = R[768 + x];
        Sxx += gx * gx; Sxy += gx * gy; Syy += gy * gy;
        float Qc = iv;  // identity warp: exact pixel
        if (!pzero) {
            const float* A = img + (size_t)(b * K_ + c) * HW;
            Qc = w00 * A[i00] + w01 * A[i01] + w10 * A[i10] + w11 * A[i11];
        }
        const float r = Qc - tc * mm;
        vx += gx * r;
        vy += gy * r;
        const int sh = (c & 1) * 16;
        imgp[c >> 1]     |= ((unsigned int)f2bf(iv)) << sh;
        tgp[c >> 1]      |= ((unsigned int)f2bf(tc)) << sh;
        tgp[4 + (c >> 1)]|= ((unsigned int)f2bf(gx)) << sh;
        tgp[8 + (c >> 1)]|= ((unsigned int)f2bf(gy)) << sh;
    }
    const size_t gpx = (size_t)b * HW + px;
    imgT[gpx] = make_uint4(imgp[0], imgp[1], imgp[2], imgp[3]);
    uint4* tg = TG + gpx * 3;
    tg[0] = make_uint4(tgp[0], tgp[1], tgp[2],  tgp[3]);
    tg[1] = make_uint4(tgp[4], tgp[5], tgp[6],  tgp[7]);
    tg[2] = make_uint4(tgp[8], tgp[9], tgp[10], tgp[11]);
    __syncthreads();   // rows consumed; reuse smem for the moment reduce

    // ---- 15 row-moments: M[k*5+n] = sum_x S_k * X^n ----
    {
        const float X2 = X * X;
        const float Xp[5] = {1.f, X, X2, X2 * X, X2 * X2};
        #pragma unroll
        for (int n = 0; n < 5; ++n) {
            smem[n * 256 + tid]        = Sxx * Xp[n];
            smem[(5 + n) * 256 + tid]  = Sxy * Xp[n];
            smem[(10 + n) * 256 + tid] = Syy * Xp[n];
        }
    }
    __syncthreads();
    {
        const int e = tid >> 5, l = tid & 31;
        float v = 0.f;
        #pragma unroll
        for (int j = 0; j < 8; ++j) v += smem[e * 256 + l + 32 * j];
        v = half_reduce(v);
        if ((tid & 31) == 0) s15[e] = v;
    }
    if (tid < 224) {
        const int e = 8 + (tid >> 5), l = tid & 31;
        float v = 0.f;
        #pragma unroll
        for (int j = 0; j < 8; ++j) v += smem[e * 256 + l + 32 * j];
        v = half_reduce(v);
        if ((tid & 31) == 0) s15[e] = v;
    }
    __syncthreads();

    // ---- assemble 36 upper-tri Gram entries from moments (f64) ----
    if (tid < 36) {
        const int aC[8]  = {1, 1, 1, 0, 0, 0, -1, -1};
        const int aNX[8] = {1, 0, 0, 0, 0, 0,  2,  1};
        const int aNY[8] = {0, 1, 0, 0, 0, 0,  0,  1};
        const int bC[8]  = {0, 0, 0, 1, 1, 1, -1, -1};
        const int bNX[8] = {0, 0, 0, 1, 0, 0,  1,  0};
        const int bNY[8] = {0, 0, 0, 0, 1, 0,  1,  2};
        const double Yd = (double)Y;
        const double Yp2 = Yd * Yd;
        const double Ypw[5] = {1.0, Yd, Yp2, Yp2 * Yd, Yp2 * Yp2};
        int p = 0, rem = tid;
        while (rem >= 8 - p) { rem -= 8 - p; ++p; }
        const int q = p + rem;
        double g = 0.0;
        const int ac = aC[p] * aC[q];
        if (ac) g += ac * Ypw[aNY[p] + aNY[q]] * (double)s15[aNX[p] + aNX[q]];
        const int ab1 = aC[p] * bC[q];
        if (ab1) g += ab1 * Ypw[aNY[p] + bNY[q]] * (double)s15[5 + aNX[p] + bNX[q]];
        const int ab2 = bC[p] * aC[q];
        if (ab2) g += ab2 * Ypw[bNY[p] + aNY[q]] * (double)s15[5 + bNX[p] + aNX[q]];
        const int bc = bC[p] * bC[q];
        if (bc) g += bc * Ypw[bNY[p] + bNY[q]] * (double)s15[10 + bNX[p] + bNX[q]];
        gramP[((size_t)b * 36 + tid) * 256 + y] = g;
    }

    // ---- iter-0 partials: J expansion + block reduce -> sPrep[b][e][y] ----
    float a[8];
    a[0] = X * vx; a[1] = Y * vx; a[2] = vx;
    a[3] = X * vy; a[4] = Y * vy; a[5] = vy;
    const float cc = a[0] + a[4];
    a[6] = -X * cc; a[7] = -Y * cc;
    __syncthreads();   // moments reads done; reuse smem again
    #pragma unroll
    for (int e = 0; e < 8; ++e) smem[e * 256 + tid] = a[e];
    __syncthreads();
    {
        const int e = tid >> 5, l = tid & 31;
        float v = 0.f;
        #pragma unroll
        for (int j = 0; j < 8; ++j) v += smem[e * 256 + l + 32 * j];
        v = half_reduce(v);
        if ((tid & 31) == 0) sPrep[b * 2048 + e * 256 + y] = v;
    }
}

// ---------------------------------------------------------------------------
// iter k (k = 1..9): blocks 0..511 reconstruct (p_k, dp_k) then accumulate
// residual partials. k==1: recon solves H dp = s0 directly (GJ, augmented
// column) since invH is produced concurrently by blocks 512..519 of this
// same dispatch (for use by k>=2). 512(+8) blocks x 256 thr.
// ---------------------------------------------------------------------------
__global__ __launch_bounds__(256) void iter_kernel(
    const uint4* __restrict__ imgT, const uint4* __restrict__ TG,
    const double* __restrict__ gramP, double* __restrict__ invHg,
    const double* __restrict__ invH, const float* __restrict__ init_param,
    const double* __restrict__ stateR, double* __restrict__ stateW,
    const float* __restrict__ sPrev, float* __restrict__ sNext,
    const float* __restrict__ sPrep,
    const int* __restrict__ max_itr, int iter) {
    if (iter >= *max_itr) return;
    __shared__ float red[2048];
    __shared__ float s8[8];
    __shared__ double sh_invH[64];
    __shared__ double sh_st[16];
    __shared__ double sh_pd[16];
    __shared__ double gpart[144];
    __shared__ double shA[64];
    __shared__ double shB[64];
    const int tid = threadIdx.x;

    if (iter == 1 && blockIdx.x >= 512) {
        // ---- inversion for batch b (for iterations 2..9) ----
        const int b = blockIdx.x - 512;
        if (tid < 144) {
            const int e = tid >> 2, q = tid & 3;
            const double* gp = gramP + ((size_t)b * 36 + e) * 256 + q * 64;
            double acc = 0.0;
            #pragma unroll 8
            for (int i = 0; i < 64; ++i) acc += gp[i];
            gpart[tid] = acc;
        }
        __syncthreads();
        const int i = tid >> 3, j = tid & 7;
        if (tid < 64) {
            const int pp = min(i, j), qq = max(i, j);
            const int tri = 8 * pp - (pp * (pp - 1)) / 2 + (qq - pp);
            shA[tid] = gpart[tri * 4] + gpart[tri * 4 + 1]
                     + gpart[tri * 4 + 2] + gpart[tri * 4 + 3];
            shB[tid] = (i == j) ? 1.0 : 0.0;
        }
        __syncthreads();
        for (int k = 0; k < 8; ++k) {
            const double piv = shA[k * 8 + k];
            __syncthreads();
            if (tid < 64 && i == k) { shA[tid] /= piv; shB[tid] /= piv; }
            __syncthreads();
            double f = 0, ak = 0, bk = 0;
            if (tid < 64) { f = shA[i * 8 + k]; ak = shA[k * 8 + j]; bk = shB[k * 8 + j]; }
            __syncthreads();
            if (tid < 64 && i != k) { shA[tid] -= f * ak; shB[tid] -= f * bk; }
            __syncthreads();
        }
        if (tid < 64) invHg[b * 64 + tid] = shB[tid];
        return;
    }

    const int b   = blockIdx.x & 7;
    const int yb  = blockIdx.x >> 3;       // 0..63, rows 4*yb .. 4*yb+3

    // ---- preload (iters >= 2 only; iter 1 solves from gramP) ----
    if (iter > 1) {
        if (tid < 64) sh_invH[tid] = invH[b * 64 + tid];
        if (tid >= 64 && tid < 72) sh_st[tid - 64] = stateR[b * 8 + (tid - 64)];
        if (tid >= 72 && tid < 80) sh_st[tid - 64] = stateR[64 + b * 8 + (tid - 72)];
    }

    // ---- stage A: state reconstruction (redundant per block) ----
    if (iter == 1) {
        // s0 from prep's per-row partials (256-wide)
        const float* sb = sPrep + b * 2048;
        {
            const int e = tid >> 5, l = tid & 31;
            float v = 0.f;
            #pragma unroll
            for (int j = 0; j < 8; ++j) v += sb[e * 256 + l + 32 * j];
            v = half_reduce(v);
            if ((tid & 31) == 0) s8[tid >> 5] = v;
        }
        if (tid < 144) {
            const int e = tid >> 2, q = tid & 3;
            const double* gp = gramP + ((size_t)b * 36 + e) * 256 + q * 64;
            double acc = 0.0;
            #pragma unroll 8
            for (int i = 0; i < 64; ++i) acc += gp[i];
            gpart[tid] = acc;
        }
        __syncthreads();
        const int i = tid >> 3, j = tid & 7;
        if (tid < 64) {
            const int pp = min(i, j), qq = max(i, j);
            const int tri = 8 * pp - (pp * (pp - 1)) / 2 + (qq - pp);
            shA[tid] = gpart[tri * 4] + gpart[tri * 4 + 1]
                     + gpart[tri * 4 + 2] + gpart[tri * 4 + 3];
            shB[tid] = (j == 0) ? (double)s8[i] : 0.0;   // augmented column
        }
        __syncthreads();
        for (int k = 0; k < 8; ++k) {
            const double piv = shA[k * 8 + k];
            __syncthreads();
            if (tid < 64 && i == k) { shA[tid] /= piv; shB[tid] /= piv; }
            __syncthreads();
            double f = 0, ak = 0, bk = 0;
            if (tid < 64) { f = shA[i * 8 + k]; ak = shA[k * 8 + j]; bk = shB[k * 8 + j]; }
            __syncthreads();
            if (tid < 64 && i != k) { shA[tid] -= f * ak; shB[tid] -= f * bk; }
            __syncthreads();
        }
        if (tid < 8) {
            // dp0 = ones -> norm sqrt(8) > 1e-3 -> active
            const double dpn = (tid < 6) ? shB[tid * 8] : 0.0;
            sh_pd[tid]     = (double)init_param[b * 8 + tid] - dpn;
            sh_pd[8 + tid] = dpn;
        }
        __syncthreads();
    } else {
        const float* sR = sPrev + b * 512;
        const int e = tid >> 5, l = tid & 31;
        float v = sR[e * 64 + l] + sR[e * 64 + 32 + l];
        v = half_reduce(v);
        if ((tid & 31) == 0) s8[tid >> 5] = v;
        __syncthreads();
        if (tid < 8) {
            double nrm2 = 0.0;
            #pragma unroll
            for (int k2 = 0; k2 < 8; ++k2) {
                const double d = sh_st[8 + k2];
                nrm2 += d * d;
            }
            double dpn = 0.0;
            if (tid < 6) {
                #pragma unroll
                for (int k2 = 0; k2 < 8; ++k2)
                    dpn += sh_invH[tid * 8 + k2] * (double)s8[k2];
            }
            const double dp2 = (sqrt(nrm2) > 1e-3) ? dpn : 0.0;
            sh_pd[tid]     = sh_st[tid] - dp2;
            sh_pd[8 + tid] = dp2;
        }
        __syncthreads();
    }
    if (yb == 0 && tid < 8) {
        stateW[b * 8 + tid]      = sh_pd[tid];
        stateW[64 + b * 8 + tid] = sh_pd[8 + tid];
    }

    const float h00 = 1.f + (float)sh_pd[0], h01 = (float)sh_pd[1], h02 = (float)sh_pd[2];
    const float h10 = (float)sh_pd[3], h11 = 1.f + (float)sh_pd[4], h12 = (float)sh_pd[5];
    const float h20 = (float)sh_pd[6], h21 = (float)sh_pd[7];

    // ---- stage B: 4 pixels/thread (rolled — R8-best config) ----
    float aa[8];
    #pragma unroll
    for (int e = 0; e < 8; ++e) aa[e] = 0.f;
    #pragma unroll 1
    for (int sub = 0; sub < 4; ++sub) {
        pixel_accum(imgT, TG, b, tid, yb * 4 + sub,
                    h00, h01, h02, h10, h11, h12, h20, h21, aa);
    }

    // ---- block reduce: [e][256] scatter -> strided read -> 32-lane shfl ----
    #pragma unroll
    for (int e = 0; e < 8; ++e) red[e * 256 + tid] = aa[e];
    __syncthreads();
    {
        const int e = tid >> 5, l = tid & 31;
        float v = 0.f;
        #pragma unroll
        for (int j = 0; j < 8; ++j) v += red[e * 256 + l + 32 * j];
        v = half_reduce(v);
        if ((tid & 31) == 0) sNext[b * 512 + e * 64 + yb] = v;
    }
}

// ---------------------------------------------------------------------------
// output: final update (direct GJ solve of H dp = s_last; works for any
// max_itr incl. 1 where invH never existed) + write p, H.
// grid = B_ blocks, 256 threads.
// ---------------------------------------------------------------------------
__global__ void output_kernel(const double* __restrict__ gramP,
                              const float* __restrict__ init_param,
                              const double* __restrict__ st0,
                              const double* __restrict__ st1,
                              const float* __restrict__ sP0,
                              const float* __restrict__ sP1,
                              const float* __restrict__ sPrep,
                              const int* __restrict__ max_itr,
                              float* __restrict__ out) {
    const int b   = blockIdx.x;
    const int tid = threadIdx.x;
    const int mi_raw = *max_itr;
    const int mi = (mi_raw > 10) ? 10 : mi_raw;
    if (mi <= 0) {
        if (tid < 8) out[b * 8 + tid] = init_param[b * 8 + tid];
        if (tid < 9) {
            float v = (tid < 8) ? init_param[b * 8 + tid] : 0.f;
            if (tid == 0 || tid == 4 || tid == 8) v += 1.f;
            out[64 + b * 9 + tid] = v;
        }
        return;
    }
    __shared__ float s8[8];
    __shared__ double sh_prev[16];
    __shared__ double gpart[144];
    __shared__ double shA[64];
    __shared__ double shB[64];

    if (mi == 1) {
        const float* sb = sPrep + b * 2048;
        const int e = tid >> 5, l = tid & 31;
        float v = 0.f;
        #pragma unroll
        for (int j = 0; j < 8; ++j) v += sb[e * 256 + l + 32 * j];
        v = half_reduce(v);
        if ((tid & 31) == 0) s8[tid >> 5] = v;
        if (tid < 8) {
            sh_prev[tid]     = (double)init_param[b * 8 + tid];
            sh_prev[8 + tid] = 1.0;
        }
    } else {
        const int pr = (mi - 1) & 1;
        const double* st = pr ? st1 : st0;
        const float*  sP = pr ? sP1 : sP0;
        const float* sb = sP + b * 512;
        const int e = tid >> 5, l = tid & 31;
        float v = sb[e * 64 + l] + sb[e * 64 + 32 + l];
        v = half_reduce(v);
        if ((tid & 31) == 0) s8[tid >> 5] = v;
        if (tid < 8) {
            sh_prev[tid]     = st[b * 8 + tid];
            sh_prev[8 + tid] = st[64 + b * 8 + tid];
        }
    }
    if (tid < 144) {
        const int e = tid >> 2, q = tid & 3;
        const double* gp = gramP + ((size_t)b * 36 + e) * 256 + q * 64;
        double acc = 0.0;
        #pragma unroll 8
        for (int i = 0; i < 64; ++i) acc += gp[i];
        gpart[tid] = acc;
    }
    __syncthreads();
    const int i = tid >> 3, j = tid & 7;
    if (tid < 64) {
        const int pp = min(i, j), qq = max(i, j);
        const int tri = 8 * pp - (pp * (pp - 1)) / 2 + (qq - pp);
        shA[tid] = gpart[tri * 4] + gpart[tri * 4 + 1]
                 + gpart[tri * 4 + 2] + gpart[tri * 4 + 3];
        shB[tid] = (j == 0) ? (double)s8[i] : 0.0;
    }
    __syncthreads();
    for (int k = 0; k < 8; ++k) {
        const double piv = shA[k * 8 + k];
        __syncthreads();
        if (tid < 64 && i == k) { shA[tid] /= piv; shB[tid] /= piv; }
        __syncthreads();
        double f = 0, ak = 0, bk = 0;
        if (tid < 64) { f = shA[i * 8 + k]; ak = shA[k * 8 + j]; bk = shB[k * 8 + j]; }
        __syncthreads();
        if (tid < 64 && i != k) { shA[tid] -= f * ak; shB[tid] -= f * bk; }
        __syncthreads();
    }
    if (tid < 8) {
        double nrm2 = 0.0;
        #pragma unroll
        for (int k2 = 0; k2 < 8; ++k2) {
            const double d = sh_prev[8 + k2];
            nrm2 += d * d;
        }
        const double dpn = (tid < 6) ? shB[tid * 8] : 0.0;
        const double dp2 = (sqrt(nrm2) > 1e-3) ? dpn : 0.0;
        const float pf = (float)(sh_prev[tid] - dp2);
        s8[tid] = pf;   // stash (rhs no longer needed)
        out[b * 8 + tid] = pf;
    }
    __syncthreads();
    if (tid < 9) {
        float v2 = (tid < 8) ? s8[tid] : 0.f;
        if (tid == 0 || tid == 4 || tid == 8) v2 += 1.f;
        out[64 + b * 9 + tid] = v2;
    }
}

extern "C" void kernel_launch(void* const* d_in, const int* in_sizes, int n_in,
                              void* d_out, int out_size, void* d_ws, size_t ws_size,
                              hipStream_t stream) {
    const float* img        = (const float*)d_in[0];
    const float* temp       = (const float*)d_in[1];
    const float* init_param = (const float*)d_in[2];
    const int*   max_itr    = (const int*)d_in[3];
    float* out = (float*)d_out;

    char* w = (char*)d_ws;
    double* gramP = (double*)w;              // 8*36*256 d = 576 KB
    double* st0   = gramP + 73728;           // 128 d (p + dp)
    double* st1   = st0 + 128;               // 128 d
    double* invH  = st1 + 128;               // 512 d
    float*  sP0   = (float*)(invH + 512);    // 8*512 f = 16 KB
    float*  sP1   = sP0 + 4096;              // 16 KB
    float*  sPrep = sP1 + 4096;              // 8*2048 f = 64 KB
    uint4* imgT   = (uint4*)(w + 1048576);           // 8.39 MB (bf16 x8 per px)
    uint4* TG     = (uint4*)(w + 1048576 + 8388608); // 25.2 MB (T,gx,gy bf16 x8)

    prep_kernel<<<B_ * H_, 256, 0, stream>>>(img, temp, init_param,
                                             imgT, TG, gramP, sPrep);
    for (int it = 1; it < 10; ++it) {
        const double* stR = (it & 1) ? st0 : st1;
        double*       stW = (it & 1) ? st1 : st0;
        const float*  sR  = (it & 1) ? sP0 : sP1;
        float*        sW  = (it & 1) ? sP1 : sP0;
        const int grid = (it == 1) ? 520 : 512;
        iter_kernel<<<grid, 256, 0, stream>>>(imgT, TG, gramP, invH, invH,
                                              init_param, stR, stW, sR, sW,
                                              sPrep, max_itr, it);
    }
    output_kernel<<<B_, 256, 0, stream>>>(gramP, init_param, st0, st1,
                                          sP0, sP1, sPrep, max_itr, out);
}

// Round 15
// 162.697 us; speedup vs baseline: 1.0453x; 1.0453x over previous
//
#include <hip/hip_runtime.h>
#include <hip/hip_bf16.h>

#define B_ 8
#define K_ 8
#define H_ 256
#define W_ 256
#define HW (H_*W_)

// ---------------------------------------------------------------------------
// helpers
// ---------------------------------------------------------------------------
__device__ __forceinline__ unsigned short f2bf(float f) {
    __hip_bfloat16 h = __float2bfloat16(f);  // RNE
    return *reinterpret_cast<unsigned short*>(&h);
}
// unpack 8 bf16 (elem 2k in low 16 bits, 2k+1 in high) to f32
__device__ __forceinline__ void ub8(uint4 u, float* o) {
    o[0] = __uint_as_float(u.x << 16); o[1] = __uint_as_float(u.x & 0xffff0000u);
    o[2] = __uint_as_float(u.y << 16); o[3] = __uint_as_float(u.y & 0xffff0000u);
    o[4] = __uint_as_float(u.z << 16); o[5] = __uint_as_float(u.z & 0xffff0000u);
    o[6] = __uint_as_float(u.w << 16); o[7] = __uint_as_float(u.w & 0xffff0000u);
}
// sum within each 32-lane half of a wave; result valid in lanes 0 and 32
__device__ __forceinline__ float half_reduce(float v) {
    v += __shfl_down(v, 16, 64);
    v += __shfl_down(v, 8, 64);
    v += __shfl_down(v, 4, 64);
    v += __shfl_down(v, 2, 64);
    v += __shfl_down(v, 1, 64);
    return v;
}

// per-pixel warp + bilinear + residual; accumulates into aa[8]
__device__ __forceinline__ void pixel_accum(
    const uint4* __restrict__ imgT, const uint4* __restrict__ TG,
    int b, int x, int y,
    float h00, float h01, float h02, float h10, float h11, float h12,
    float h20, float h21, float* aa) {
    const int px = (y << 8) | x;
    const float X = (float)x - 127.5f, Y = (float)y - 127.5f;
    const float zw = h20 * X + h21 * Y + 1.f;
    const float Xw = (h00 * X + h01 * Y + h02) / zw + 127.5f;
    const float Yw = (h10 * X + h11 * Y + h12) / zw + 127.5f;
    const float NLO = -1.f + 2.f / 256.f, NHI = 1.f - 2.f / 256.f;
    const float xn = Xw / 127.5f - 1.f, yn = Yw / 127.5f - 1.f;
    const float m = (xn > NLO && xn < NHI && yn > NLO && yn < NHI) ? 1.f : 0.f;

    const float x0f = floorf(Xw), y0f = floorf(Yw);
    const float fx = Xw - x0f, fy = Yw - y0f;
    const float x1f = x0f + 1.f, y1f = y0f + 1.f;
    const bool vx0 = (x0f >= 0.f) && (x0f <= 255.f);
    const bool vx1 = (x1f >= 0.f) && (x1f <= 255.f);
    const bool vy0 = (y0f >= 0.f) && (y0f <= 255.f);
    const bool vy1 = (y1f >= 0.f) && (y1f <= 255.f);
    const int xi0 = (int)fminf(fmaxf(x0f, 0.f), 255.f);
    const int xi1 = (int)fminf(fmaxf(x1f, 0.f), 255.f);
    const int yi0 = (int)fminf(fmaxf(y0f, 0.f), 255.f);
    const int yi1 = (int)fminf(fmaxf(y1f, 0.f), 255.f);
    const int i00 = yi0 * W_ + xi0, i01 = yi0 * W_ + xi1;
    const int i10 = yi1 * W_ + xi0, i11 = yi1 * W_ + xi1;
    const float w00 = ((vx0 && vy0) ? 1.f : 0.f) * (1.f - fx) * (1.f - fy);
    const float w01 = ((vx1 && vy0) ? 1.f : 0.f) * fx * (1.f - fy);
    const float w10 = ((vx0 && vy1) ? 1.f : 0.f) * (1.f - fx) * fy;
    const float w11 = ((vx1 && vy1) ? 1.f : 0.f) * fx * fy;

    const int base = b * HW;
    const uint4 u00 = imgT[base + i00], u01 = imgT[base + i01];
    const uint4 u10 = imgT[base + i10], u11 = imgT[base + i11];
    const uint4* tg = TG + (size_t)(base + px) * 3;
    const uint4 t0 = tg[0], g0 = tg[1], g1 = tg[2];

    float A00[8], A01[8], A10[8], A11[8], GX[8], GY[8], TV[8];
    ub8(u00, A00); ub8(u01, A01); ub8(u10, A10); ub8(u11, A11);
    ub8(t0, TV);   ub8(g0, GX);   ub8(g1, GY);

    float vx = 0.f, vy = 0.f;
    #pragma unroll
    for (int c = 0; c < 8; ++c) {
        const float Q = w00 * A00[c] + w01 * A01[c] + w10 * A10[c] + w11 * A11[c];
        const float r = Q - TV[c] * m;
        vx += GX[c] * r;
        vy += GY[c] * r;
    }
    const float t0a = X * vx, t4a = Y * vy;
    const float cc = t0a + t4a;
    aa[0] += t0a;      aa[1] += Y * vx;  aa[2] += vx;
    aa[3] += X * vy;   aa[4] += t4a;     aa[5] += vy;
    aa[6] -= X * cc;   aa[7] -= Y * cc;
}

// ---------------------------------------------------------------------------
// prep: transpose img/temp to channel-interleaved bf16 + grads; Gram via
// 15 row-moments (Y constant per block; Jacobian components are monomials
// in X,Y, so G entries = Y-powers x Sum S_k X^n). grid = B_*H_ blocks, 256 thr.
// ---------------------------------------------------------------------------
__global__ __launch_bounds__(256) void prep_kernel(
    const float* __restrict__ img, const float* __restrict__ temp,
    uint4* __restrict__ imgT, uint4* __restrict__ TG,
    double* __restrict__ gramP) {
    __shared__ float smem[8192];
    __shared__ float s15[15];
    const int b   = blockIdx.x & 7;
    const int y   = blockIdx.x >> 3;
    const int tid = threadIdx.x;
    const int ym = (y > 0) ? y - 1 : 0;
    const int yp = (y < 255) ? y + 1 : 255;

    #pragma unroll
    for (int j = 0; j < 8; ++j) {
        const int slot = tid + 256 * j;
        const int rowid = slot >> 6, col4 = slot & 63;
        const int c = rowid >> 2, sel = rowid & 3;
        const int sy = (sel == 0) ? ym : ((sel == 2) ? yp : y);
        const float* src = ((sel == 3) ? img : temp)
                         + ((size_t)(b * K_ + c) * HW + sy * W_ + col4 * 4);
        const float4 v = *(const float4*)src;
        *(float4*)&smem[(c * 4 + sel) * 256 + col4 * 4] = v;
    }
    __syncthreads();

    const int x = tid;
    const int px = (y << 8) | x;
    const float X = (float)x - 127.5f, Y = (float)y - 127.5f;
    const int xm = (x > 0) ? x - 1 : 0;
    const int xp = (x < 255) ? x + 1 : 255;
    float Sxx = 0.f, Sxy = 0.f, Syy = 0.f;
    unsigned int imgp[4] = {0, 0, 0, 0};
    unsigned int tgp[12];
    #pragma unroll
    for (int i = 0; i < 12; ++i) tgp[i] = 0u;
    #pragma unroll
    for (int c = 0; c < 8; ++c) {
        const float* R = &smem[c * 1024];
        const float gx = 0.5f * (R[256 + xp] - R[256 + xm]);
        const float gy = 0.5f * (R[512 + x] - R[x]);
        const float tc = R[256 + x];
        const float iv = R[768 + x];
        Sxx += gx * gx; Sxy += gx * gy; Syy += gy * gy;
        const int sh = (c & 1) * 16;
        imgp[c >> 1]     |= ((unsigned int)f2bf(iv)) << sh;
        tgp[c >> 1]      |= ((unsigned int)f2bf(tc)) << sh;
        tgp[4 + (c >> 1)]|= ((unsigned int)f2bf(gx)) << sh;
        tgp[8 + (c >> 1)]|= ((unsigned int)f2bf(gy)) << sh;
    }
    const size_t gpx = (size_t)b * HW + px;
    imgT[gpx] = make_uint4(imgp[0], imgp[1], imgp[2], imgp[3]);
    uint4* tg = TG + gpx * 3;
    tg[0] = make_uint4(tgp[0], tgp[1], tgp[2],  tgp[3]);
    tg[1] = make_uint4(tgp[4], tgp[5], tgp[6],  tgp[7]);
    tg[2] = make_uint4(tgp[8], tgp[9], tgp[10], tgp[11]);
    __syncthreads();   // rows consumed; reuse smem for the moment reduce

    // ---- 15 row-moments: M[k*5+n] = sum_x S_k * X^n ----
    {
        const float X2 = X * X;
        const float Xp[5] = {1.f, X, X2, X2 * X, X2 * X2};
        #pragma unroll
        for (int n = 0; n < 5; ++n) {
            smem[n * 256 + tid]        = Sxx * Xp[n];
            smem[(5 + n) * 256 + tid]  = Sxy * Xp[n];
            smem[(10 + n) * 256 + tid] = Syy * Xp[n];
        }
    }
    __syncthreads();
    {
        const int e = tid >> 5, l = tid & 31;
        float v = 0.f;
        #pragma unroll
        for (int j = 0; j < 8; ++j) v += smem[e * 256 + l + 32 * j];
        v = half_reduce(v);
        if ((tid & 31) == 0) s15[e] = v;
    }
    if (tid < 224) {
        const int e = 8 + (tid >> 5), l = tid & 31;
        float v = 0.f;
        #pragma unroll
        for (int j = 0; j < 8; ++j) v += smem[e * 256 + l + 32 * j];
        v = half_reduce(v);
        if ((tid & 31) == 0) s15[e] = v;
    }
    __syncthreads();

    // ---- assemble 36 upper-tri entries from moments (f64) ----
    if (tid < 36) {
        // J row p: a_p (coeff on gx) and b_p (coeff on gy) are monomials
        const int aC[8]  = {1, 1, 1, 0, 0, 0, -1, -1};
        const int aNX[8] = {1, 0, 0, 0, 0, 0,  2,  1};
        const int aNY[8] = {0, 1, 0, 0, 0, 0,  0,  1};
        const int bC[8]  = {0, 0, 0, 1, 1, 1, -1, -1};
        const int bNX[8] = {0, 0, 0, 1, 0, 0,  1,  0};
        const int bNY[8] = {0, 0, 0, 0, 1, 0,  1,  2};
        const double Yd = (double)Y;
        const double Yp2 = Yd * Yd;
        const double Ypw[5] = {1.0, Yd, Yp2, Yp2 * Yd, Yp2 * Yp2};
        int p = 0, rem = tid;
        while (rem >= 8 - p) { rem -= 8 - p; ++p; }
        const int q = p + rem;
        double g = 0.0;
        const int ac = aC[p] * aC[q];
        if (ac) g += ac * Ypw[aNY[p] + aNY[q]] * (double)s15[aNX[p] + aNX[q]];
        const int ab1 = aC[p] * bC[q];
        if (ab1) g += ab1 * Ypw[aNY[p] + bNY[q]] * (double)s15[5 + aNX[p] + bNX[q]];
        const int ab2 = bC[p] * aC[q];
        if (ab2) g += ab2 * Ypw[bNY[p] + aNY[q]] * (double)s15[5 + bNX[p] + aNX[q]];
        const int bc = bC[p] * bC[q];
        if (bc) g += bc * Ypw[bNY[p] + bNY[q]] * (double)s15[10 + bNX[p] + bNX[q]];
        gramP[((size_t)b * 36 + tid) * 256 + y] = g;
    }
}

// ---------------------------------------------------------------------------
// iter k: blocks 0..511 do state recon + residual accumulation; on iter 0,
// blocks 512..519 instead do the Gram reduce + f64 Gauss-Jordan inversion
// (iter0 itself doesn't need invH; iter1 reads it across the dispatch
// boundary). 512(+8) blocks x 256 thr.
// ---------------------------------------------------------------------------
__global__ __launch_bounds__(256) void iter_kernel(
    const uint4* __restrict__ imgT, const uint4* __restrict__ TG,
    const double* __restrict__ gramP, double* __restrict__ invHg,
    const double* __restrict__ invH, const float* __restrict__ init_param,
    const double* __restrict__ stateR, double* __restrict__ stateW,
    const float* __restrict__ sPrev, float* __restrict__ sNext,
    const int* __restrict__ max_itr, int iter) {
    if (iter >= *max_itr) return;
    __shared__ float red[2048];
    __shared__ float s8[8];
    __shared__ double sh_invH[64];
    __shared__ double sh_st[16];
    __shared__ double sh_pd[16];
    const int tid = threadIdx.x;

    if (iter == 0 && blockIdx.x >= 512) {
        // ---- inversion for batch b (runs once, inside iter0's dispatch) ----
        const int b = blockIdx.x - 512;
        __shared__ double gpart[144];
        __shared__ double shA[64];
        __shared__ double shB[64];
        if (tid < 144) {
            const int e = tid >> 2, q = tid & 3;
            const double* gp = gramP + ((size_t)b * 36 + e) * 256 + q * 64;
            double acc = 0.0;
            #pragma unroll 8
            for (int i = 0; i < 64; ++i) acc += gp[i];
            gpart[tid] = acc;
        }
        __syncthreads();
        const int i = tid >> 3, j = tid & 7;
        if (tid < 64) {
            const int pp = min(i, j), qq = max(i, j);
            const int tri = 8 * pp - (pp * (pp - 1)) / 2 + (qq - pp);
            shA[tid] = gpart[tri * 4] + gpart[tri * 4 + 1]
                     + gpart[tri * 4 + 2] + gpart[tri * 4 + 3];
            shB[tid] = (i == j) ? 1.0 : 0.0;
        }
        __syncthreads();
        for (int k = 0; k < 8; ++k) {
            const double piv = shA[k * 8 + k];
            __syncthreads();
            if (tid < 64 && i == k) { shA[tid] /= piv; shB[tid] /= piv; }
            __syncthreads();
            double f = 0, ak = 0, bk = 0;
            if (tid < 64) { f = shA[i * 8 + k]; ak = shA[k * 8 + j]; bk = shB[k * 8 + j]; }
            __syncthreads();
            if (tid < 64 && i != k) { shA[tid] -= f * ak; shB[tid] -= f * bk; }
            __syncthreads();
        }
        if (tid < 64) invHg[b * 64 + tid] = shB[tid];
        return;
    }

    const int b   = blockIdx.x & 7;
    const int yb  = blockIdx.x >> 3;       // 0..63, rows 4*yb .. 4*yb+3

    // ---- preload (independent loads issue before the dependent chain) ----
    if (iter > 0) {
        if (tid < 64) sh_invH[tid] = invH[b * 64 + tid];
        if (tid >= 64 && tid < 72) sh_st[tid - 64] = stateR[b * 8 + (tid - 64)];
        if (tid >= 72 && tid < 80) sh_st[tid - 64] = stateR[64 + b * 8 + (tid - 72)];
    }

    // ---- stage A: state reconstruction (redundant per block) ----
    if (iter == 0) {
        if (tid < 8) {
            sh_pd[tid]     = (double)init_param[b * 8 + tid];
            sh_pd[8 + tid] = 1.0;
        }
        __syncthreads();
    } else {
        const float* sR = sPrev + b * 512;
        const int e = tid >> 5, l = tid & 31;
        float v = sR[e * 64 + l] + sR[e * 64 + 32 + l];
        v = half_reduce(v);
        if ((tid & 31) == 0) s8[tid >> 5] = v;
        __syncthreads();
        if (tid < 8) {
            double nrm2 = 0.0;
            #pragma unroll
            for (int k2 = 0; k2 < 8; ++k2) {
                const double d = sh_st[8 + k2];
                nrm2 += d * d;
            }
            double dpn = 0.0;
            if (tid < 6) {
                #pragma unroll
                for (int k2 = 0; k2 < 8; ++k2)
                    dpn += sh_invH[tid * 8 + k2] * (double)s8[k2];
            }
            const double dp2 = (sqrt(nrm2) > 1e-3) ? dpn : 0.0;
            sh_pd[tid]     = sh_st[tid] - dp2;
            sh_pd[8 + tid] = dp2;
        }
        __syncthreads();
    }
    if (yb == 0 && tid < 8) {
        stateW[b * 8 + tid]      = sh_pd[tid];
        stateW[64 + b * 8 + tid] = sh_pd[8 + tid];
    }

    const float h00 = 1.f + (float)sh_pd[0], h01 = (float)sh_pd[1], h02 = (float)sh_pd[2];
    const float h10 = (float)sh_pd[3], h11 = 1.f + (float)sh_pd[4], h12 = (float)sh_pd[5];
    const float h20 = (float)sh_pd[6], h21 = (float)sh_pd[7];

    // ---- stage B: 4 pixels/thread (rolled — R8-best config) ----
    float aa[8];
    #pragma unroll
    for (int e = 0; e < 8; ++e) aa[e] = 0.f;
    #pragma unroll 1
    for (int sub = 0; sub < 4; ++sub) {
        pixel_accum(imgT, TG, b, tid, yb * 4 + sub,
                    h00, h01, h02, h10, h11, h12, h20, h21, aa);
    }

    // ---- block reduce: [e][256] scatter -> strided read -> 32-lane shfl ----
    #pragma unroll
    for (int e = 0; e < 8; ++e) red[e * 256 + tid] = aa[e];
    __syncthreads();
    {
        const int e = tid >> 5, l = tid & 31;
        float v = 0.f;
        #pragma unroll
        for (int j = 0; j < 8; ++j) v += red[e * 256 + l + 32 * j];
        v = half_reduce(v);
        if ((tid & 31) == 0) sNext[b * 512 + e * 64 + yb] = v;
    }
}

// ---------------------------------------------------------------------------
// output: final update (reduce last compact partials) + write p, H.
// grid = B_ blocks (one per batch), 256 threads.
// ---------------------------------------------------------------------------
__global__ void output_kernel(const double* __restrict__ invH,
                              const float* __restrict__ init_param,
                              const double* __restrict__ st0,
                              const double* __restrict__ st1,
                              const float* __restrict__ sP0,
                              const float* __restrict__ sP1,
                              const int* __restrict__ max_itr,
                              float* __restrict__ out) {
    const int b   = blockIdx.x;
    const int tid = threadIdx.x;
    const int mi_raw = *max_itr;
    const int mi = (mi_raw > 10) ? 10 : mi_raw;
    if (mi <= 0) {
        if (tid < 8) out[b * 8 + tid] = init_param[b * 8 + tid];
        if (tid < 9) {
            float v = (tid < 8) ? init_param[b * 8 + tid] : 0.f;
            if (tid == 0 || tid == 4 || tid == 8) v += 1.f;
            out[64 + b * 9 + tid] = v;
        }
        return;
    }
    const int pr = (mi - 1) & 1;
    const double* st = pr ? st1 : st0;
    const float*  sP = pr ? sP1 : sP0;
    __shared__ float s8[8];
    __shared__ float sh_pf[8];
    const float* sb = sP + b * 512;
    const int e = tid >> 5, l = tid & 31;
    float v = sb[e * 64 + l] + sb[e * 64 + 32 + l];
    v = half_reduce(v);
    if ((tid & 31) == 0) s8[tid >> 5] = v;
    __syncthreads();
    if (tid < 8) {
        double nrm2 = 0.0;
        #pragma unroll
        for (int k2 = 0; k2 < 8; ++k2) {
            const double d = st[64 + b * 8 + k2];
            nrm2 += d * d;
        }
        double dpn = 0.0;
        if (tid < 6) {
            #pragma unroll
            for (int k2 = 0; k2 < 8; ++k2)
                dpn += invH[b * 64 + tid * 8 + k2] * (double)s8[k2];
        }
        const double dp2 = (sqrt(nrm2) > 1e-3) ? dpn : 0.0;
        const float pf = (float)(st[b * 8 + tid] - dp2);
        sh_pf[tid] = pf;
        out[b * 8 + tid] = pf;
    }
    __syncthreads();
    if (tid < 9) {
        float v2 = (tid < 8) ? sh_pf[tid] : 0.f;
        if (tid == 0 || tid == 4 || tid == 8) v2 += 1.f;
        out[64 + b * 9 + tid] = v2;
    }
}

extern "C" void kernel_launch(void* const* d_in, const int* in_sizes, int n_in,
                              void* d_out, int out_size, void* d_ws, size_t ws_size,
                              hipStream_t stream) {
    const float* img        = (const float*)d_in[0];
    const float* temp       = (const float*)d_in[1];
    const float* init_param = (const float*)d_in[2];
    const int*   max_itr    = (const int*)d_in[3];
    float* out = (float*)d_out;

    char* w = (char*)d_ws;
    double* gramP = (double*)w;              // 8*36*256 d = 576 KB
    double* st0   = gramP + 73728;           // 128 d (p + dp)
    double* st1   = st0 + 128;               // 128 d
    double* invH  = st1 + 128;               // 512 d
    float*  sP0   = (float*)(invH + 512);    // 8*512 f = 16 KB
    float*  sP1   = sP0 + 4096;              // 16 KB
    uint4* imgT   = (uint4*)(w + 1048576);           // 8.39 MB (bf16 x8 per px)
    uint4* TG     = (uint4*)(w + 1048576 + 8388608); // 25.2 MB (T,gx,gy bf16 x8)

    prep_kernel<<<B_ * H_, 256, 0, stream>>>(img, temp, imgT, TG, gramP);
    for (int it = 0; it < 10; ++it) {
        const double* stR = (it & 1) ? st0 : st1;
        double*       stW = (it & 1) ? st1 : st0;
        const float*  sR  = (it & 1) ? sP0 : sP1;
        float*        sW  = (it & 1) ? sP1 : sP0;
        const int grid = (it == 0) ? 520 : 512;
        iter_kernel<<<grid, 256, 0, stream>>>(imgT, TG, gramP, invH, invH,
                                              init_param, stR, stW, sR, sW,
                                              max_itr, it);
    }
    output_kernel<<<B_, 256, 0, stream>>>(invH, init_param, st0, st1,
                                          sP0, sP1, max_itr, out);
}